// Round 6
// baseline (267.618 us; speedup 1.0000x reference)
//
#include <hip/hip_runtime.h>
#include <math.h>

#define NEG 0.2f

typedef __attribute__((ext_vector_type(8))) short bf16x8;
typedef __attribute__((ext_vector_type(4))) float f32x4;
typedef unsigned int u32;

__device__ inline float bf2f(unsigned short u) {
    union { unsigned int i; float f; } v; v.i = ((unsigned int)u) << 16; return v.f;
}
__device__ inline unsigned short f2bf(float f) {
    union { float f; unsigned int i; } v; v.f = f;
    unsigned int r = v.i + 0x7FFF + ((v.i >> 16) & 1);
    return (unsigned short)(r >> 16);
}
// async global->LDS, 16B/lane; LDS dest = wave-uniform base + lane*16
__device__ inline void load_lds16(const unsigned short* g, unsigned short* l) {
    __builtin_amdgcn_global_load_lds((const __attribute__((address_space(1))) u32*)g,
                                     (__attribute__((address_space(3))) u32*)l, 16, 0, 0);
}

// ============ unified split-bf16 GEMM (128x64 tile) + fused scores ============
// A: [M,512] bf16 [Ah|Al]; Bt: [outc,768] rows [Wh;Wh;Wl]
// blockIdx.x = 64-col tile = head; C head-major [outc/64][M][64]; es/ed [outc/64][M]
__global__ __launch_bounds__(256) void gemm_scores(const unsigned short* __restrict__ A,
                                                   const unsigned short* __restrict__ Bt,
                                                   unsigned short* __restrict__ C,
                                                   const float* __restrict__ a_s,
                                                   const float* __restrict__ a_d,
                                                   float* __restrict__ es,
                                                   float* __restrict__ ed, int M) {
    __shared__ unsigned short As[128 * 32];
    __shared__ unsigned short Bs[64 * 32];
    const int tid = threadIdx.x;
    const int bm = blockIdx.y * 128, head = blockIdx.x, bn = head * 64;
    const int wave = tid >> 6, lane = tid & 63;
    const int wm = wave * 32;  // each wave: 32 rows x 64 cols
    const int lm = lane & 15, kq = lane >> 4;
    const int rA = lane >> 2, cA = (lane & 3) * 8;

    f32x4 acc[2][4] = {};
    for (int k0 = 0; k0 < 768; k0 += 32) {
        const int ka = (k0 < 512) ? k0 : k0 - 512;
#pragma unroll
        for (int i = 0; i < 2; ++i) {
            int c = wave * 2 + i;
            int gr = bm + c * 16 + rA;
            if (gr >= M) gr = M - 1;  // clamp: discarded at store
            load_lds16(A + (size_t)gr * 512 + ka + cA, &As[c * 16 * 32]);
        }
        load_lds16(Bt + (size_t)(bn + wave * 16 + rA) * 768 + k0 + cA, &Bs[wave * 16 * 32]);
        __syncthreads();
        bf16x8 af[2], bfr[4];
#pragma unroll
        for (int f = 0; f < 2; ++f) af[f] = *(const bf16x8*)(&As[(wm + f * 16 + lm) * 32 + kq * 8]);
#pragma unroll
        for (int f = 0; f < 4; ++f) bfr[f] = *(const bf16x8*)(&Bs[(f * 16 + lm) * 32 + kq * 8]);
#pragma unroll
        for (int fr = 0; fr < 2; ++fr)
#pragma unroll
            for (int fc = 0; fc < 4; ++fc)
                acc[fr][fc] = __builtin_amdgcn_mfma_f32_16x16x32_bf16(af[fr], bfr[fc], acc[fr][fc], 0, 0, 0);
        __syncthreads();
    }
    float asv[4], adv[4];
#pragma unroll
    for (int fc = 0; fc < 4; ++fc) {
        asv[fc] = a_s[head * 64 + fc * 16 + lm];
        adv[fc] = a_d[head * 64 + fc * 16 + lm];
    }
    unsigned short* Ch = C + (size_t)head * M * 64;
    float* esh = es + (size_t)head * M;
    float* edh = ed + (size_t)head * M;
#pragma unroll
    for (int fr = 0; fr < 2; ++fr)
#pragma unroll
        for (int i = 0; i < 4; ++i) {
            int row = bm + wm + fr * 16 + kq * 4 + i;
            float se = 0.f, de = 0.f;
#pragma unroll
            for (int fc = 0; fc < 4; ++fc) {
                float c = acc[fr][fc][i];
                se = fmaf(asv[fc], c, se);
                de = fmaf(adv[fc], c, de);
            }
#pragma unroll
            for (int off = 1; off < 16; off <<= 1) {
                se += __shfl_xor(se, off, 64);
                de += __shfl_xor(de, off, 64);
            }
            if (row < M) {
                if (lm == 0) { esh[row] = se; edh[row] = de; }
#pragma unroll
                for (int fc = 0; fc < 4; ++fc)
                    Ch[(size_t)row * 64 + fc * 16 + lm] = f2bf(acc[fr][fc][i]);
            }
        }
}

// ============ fused pre-pass: conv_x + conv_w(1&2) + zero(deg) ============
__global__ __launch_bounds__(256) void pre(const float* __restrict__ x,
                                           const float* __restrict__ W1,
                                           const float* __restrict__ W2,
                                           unsigned short* __restrict__ xs,
                                           unsigned short* __restrict__ Wt1,
                                           unsigned short* __restrict__ Wt2,
                                           int* __restrict__ deg,
                                           int xb, int wb, int N) {
    int b = blockIdx.x, tid = threadIdx.x;
    if (b < xb) {
        int i = b * 256 + tid;
        if (i >= N * 64) return;
        int e0 = i * 4;
        int node = e0 >> 8, c = e0 & 255;
        float4 f = *(const float4*)(x + e0);
        unsigned short h0 = f2bf(f.x), h1 = f2bf(f.y), h2 = f2bf(f.z), h3 = f2bf(f.w);
        uint2 hi, lo;
        hi.x = (u32)h0 | ((u32)h1 << 16);
        hi.y = (u32)h2 | ((u32)h3 << 16);
        lo.x = (u32)f2bf(f.x - bf2f(h0)) | ((u32)f2bf(f.y - bf2f(h1)) << 16);
        lo.y = (u32)f2bf(f.z - bf2f(h2)) | ((u32)f2bf(f.w - bf2f(h3)) << 16);
        *(uint2*)(xs + (size_t)node * 512 + c) = hi;
        *(uint2*)(xs + (size_t)node * 512 + 256 + c) = lo;
    } else if (b < xb + wb) {
        int i = (b - xb) * 256 + tid;
        const float* W;
        unsigned short* Wt;
        int outc;
        if (i < 256 * 768) { W = W1; Wt = Wt1; outc = 256; }
        else {
            i -= 256 * 768;
            if (i >= 64 * 768) return;
            W = W2; Wt = Wt2; outc = 64;
        }
        int n = i / 768, k = i % 768;
        int ksrc = (k < 256) ? k : (k < 512 ? k - 256 : k - 512);
        float f = W[(size_t)ksrc * outc + n];
        unsigned short h = f2bf(f);
        if (k >= 512) h = f2bf(f - bf2f(h));
        Wt[i] = h;
    } else {
        int i = (b - xb - wb) * 256 + tid;
        if (i < N) deg[i] = 0;
    }
}

// ============ CSR build ============
__global__ __launch_bounds__(256) void build_deg(const int* __restrict__ ei, int E, int Np,
                                                 int* __restrict__ deg) {
    int e = blockIdx.x * 256 + threadIdx.x;
    if (e >= E + Np) return;
    int d = (e < E) ? ei[E + e] : (e - E);
    atomicAdd(&deg[d], 1);
}

__global__ __launch_bounds__(1024) void scan_deg(const int* __restrict__ deg,
                                                 int* __restrict__ offs,
                                                 int* __restrict__ cursor, int n) {
    __shared__ int sums[1024];
    int t = threadIdx.x;
    int CH = (n + 1023) >> 10;
    int b = t * CH, e = min(b + CH, n);
    if (b > n) b = n;
    int s = 0;
    for (int i = b; i < e; ++i) s += deg[i];
    int val = s;
    sums[t] = val;
    __syncthreads();
    for (int off = 1; off < 1024; off <<= 1) {
        int o = (t >= off) ? sums[t - off] : 0;
        __syncthreads();
        val += o;
        sums[t] = val;
        __syncthreads();
    }
    int run = val - s;
    for (int i = b; i < e; ++i) {
        offs[i] = run;
        cursor[i] = run;
        run += deg[i];
    }
    if (t == 1023) offs[n] = val;
}

__global__ __launch_bounds__(256) void fill_csr(const int* __restrict__ ei, int E, int Np,
                                                int* __restrict__ cursor, int* __restrict__ csr) {
    int e = blockIdx.x * 256 + threadIdx.x;
    if (e >= E + Np) return;
    int s, d;
    if (e < E) { s = ei[e]; d = ei[E + e]; }
    else       { s = d = e - E; }
    int pos = atomicAdd(&cursor[d], 1);
    csr[pos] = s;
}

// ============ agg1: wave = (node, head); 4 edges/iter (16 lanes each) =========
// h: HEAD-MAJOR [4][n][64] (row=128B); es/ed: [4][n]; head = blockIdx&3 -> XCD-local
__global__ __launch_bounds__(256) void agg1(const unsigned short* __restrict__ h,
                                            const int* __restrict__ csr,
                                            const int* __restrict__ offs,
                                            const float* __restrict__ es,
                                            const float* __restrict__ ed,
                                            const float* __restrict__ b1,
                                            unsigned short* __restrict__ outs, int n) {
    const int head = blockIdx.x & 3;
    const int node = (blockIdx.x >> 2) * 4 + (threadIdx.x >> 6);
    const int lane = threadIdx.x & 63;
    if (node >= n) return;
    const int grp = lane >> 4, li = lane & 15;  // 4 edge-groups x 16 lanes
    const int ch = li * 4;                       // 4 channels per lane (uint2)
    const unsigned short* ht = h + (size_t)head * n * 64;
    const float* esh = es + (size_t)head * n;
    const float edst = ed[(size_t)head * n + node];
    const int j0 = offs[node], j1 = offs[node + 1];
    float z = 0.f;
    float a[4] = {};
    for (int j = j0; j < j1; j += 4) {
        int e = j + grp;
        bool valid = e < j1;
        int s = csr[valid ? e : j0];
        float l = esh[s] + edst;
        l = (l > 0.f) ? l : NEG * l;
        float p = valid ? __expf(l) : 0.f;
        uint2 w = *(const uint2*)(ht + (size_t)s * 64 + ch);
        z += p;
        a[0] = fmaf(p, bf2f((unsigned short)(w.x & 0xffffu)), a[0]);
        a[1] = fmaf(p, bf2f((unsigned short)(w.x >> 16)), a[1]);
        a[2] = fmaf(p, bf2f((unsigned short)(w.y & 0xffffu)), a[2]);
        a[3] = fmaf(p, bf2f((unsigned short)(w.y >> 16)), a[3]);
    }
    // combine the 4 edge-groups
#pragma unroll
    for (int off = 16; off < 64; off <<= 1) {
        z += __shfl_xor(z, off, 64);
#pragma unroll
        for (int c = 0; c < 4; ++c) a[c] += __shfl_xor(a[c], off, 64);
    }
    if (grp == 0) {
        float inv = 1.f / z;
        float r[4];
        unsigned short qh[4];
#pragma unroll
        for (int c = 0; c < 4; ++c) {
            r[c] = a[c] * inv + b1[head * 64 + ch + c];
            r[c] = (r[c] > 0.f) ? r[c] : (__expf(r[c]) - 1.f);  // ELU
            qh[c] = f2bf(r[c]);
        }
        uint2 hiw, low;
        hiw.x = (u32)qh[0] | ((u32)qh[1] << 16);
        hiw.y = (u32)qh[2] | ((u32)qh[3] << 16);
        low.x = (u32)f2bf(r[0] - bf2f(qh[0])) | ((u32)f2bf(r[1] - bf2f(qh[1])) << 16);
        low.y = (u32)f2bf(r[2] - bf2f(qh[2])) | ((u32)f2bf(r[3] - bf2f(qh[3])) << 16);
        // stacked [hi(256)|lo(256)] for GEMM2 split-bf16 input
        *(uint2*)(outs + (size_t)node * 512 + head * 64 + ch) = hiw;
        *(uint2*)(outs + (size_t)node * 512 + 256 + head * 64 + ch) = low;
    }
}

// ============ agg2: same structure, 1 head, fp32 out ============
__global__ __launch_bounds__(256) void agg2(const unsigned short* __restrict__ h,
                                            const int* __restrict__ csr,
                                            const int* __restrict__ offs,
                                            const float* __restrict__ es,
                                            const float* __restrict__ ed,
                                            const float* __restrict__ b2,
                                            float* __restrict__ out, int n) {
    const int node = blockIdx.x * 4 + (threadIdx.x >> 6);
    const int lane = threadIdx.x & 63;
    if (node >= n) return;
    const int grp = lane >> 4, li = lane & 15;
    const int ch = li * 4;
    const float edst = ed[node];
    const int j0 = offs[node], j1 = offs[node + 1];
    float z = 0.f;
    float a[4] = {};
    for (int j = j0; j < j1; j += 4) {
        int e = j + grp;
        bool valid = e < j1;
        int s = csr[valid ? e : j0];
        float l = es[s] + edst;
        l = (l > 0.f) ? l : NEG * l;
        float p = valid ? __expf(l) : 0.f;
        uint2 w = *(const uint2*)(h + (size_t)s * 64 + ch);
        z += p;
        a[0] = fmaf(p, bf2f((unsigned short)(w.x & 0xffffu)), a[0]);
        a[1] = fmaf(p, bf2f((unsigned short)(w.x >> 16)), a[1]);
        a[2] = fmaf(p, bf2f((unsigned short)(w.y & 0xffffu)), a[2]);
        a[3] = fmaf(p, bf2f((unsigned short)(w.y >> 16)), a[3]);
    }
#pragma unroll
    for (int off = 16; off < 64; off <<= 1) {
        z += __shfl_xor(z, off, 64);
#pragma unroll
        for (int c = 0; c < 4; ++c) a[c] += __shfl_xor(a[c], off, 64);
    }
    if (grp == 0) {
        float inv = 1.f / z;
        float4 r;
        r.x = a[0] * inv + b2[ch + 0];
        r.y = a[1] * inv + b2[ch + 1];
        r.z = a[2] * inv + b2[ch + 2];
        r.w = a[3] * inv + b2[ch + 3];
        *(float4*)(out + (size_t)node * 64 + ch) = r;
    }
}

// ============ launch ============
extern "C" void kernel_launch(void* const* d_in, const int* in_sizes, int n_in,
                              void* d_out, int out_size, void* d_ws, size_t ws_size,
                              hipStream_t stream) {
    const float* x   = (const float*)d_in[0];
    const int*   ei  = (const int*)d_in[1];
    const float* W1  = (const float*)d_in[2];
    const float* a1s = (const float*)d_in[3];
    const float* a1d = (const float*)d_in[4];
    const float* b1  = (const float*)d_in[5];
    const float* W2  = (const float*)d_in[6];
    const float* a2s = (const float*)d_in[7];
    const float* a2d = (const float*)d_in[8];
    const float* b2  = (const float*)d_in[9];
    float* out = (float*)d_out;

    const int N = in_sizes[0] / 256;   // 20000
    const int E = in_sizes[1] / 2;     // 320000
    const int EP = E + N;

    char* p = (char*)d_ws;
    auto take = [&](size_t bytes) {
        char* r = p;
        p += (bytes + 255) & ~(size_t)255;
        return r;
    };
    int* deg    = (int*)take((size_t)N * 4);
    int* offs   = (int*)take((size_t)(N + 1) * 4);
    int* cursor = (int*)take((size_t)N * 4);
    int* csr    = (int*)take((size_t)EP * 4);
    unsigned short* hstk = (unsigned short*)take((size_t)N * 512 * 2); // x' then h1a' (aliased)
    unsigned short* Wt1  = (unsigned short*)take((size_t)256 * 768 * 2);
    unsigned short* Wt2  = (unsigned short*)take((size_t)64 * 768 * 2);
    unsigned short* h1   = (unsigned short*)take((size_t)N * 256 * 2);  // head-major [4][N][64]
    unsigned short* h2   = (unsigned short*)take((size_t)N * 64 * 2);
    float* es1 = (float*)take((size_t)N * 4 * 4);  // head-major [4][N]
    float* ed1 = (float*)take((size_t)N * 4 * 4);
    float* es2 = (float*)take((size_t)N * 4);
    float* ed2 = (float*)take((size_t)N * 4);

    // K1: conv_x + conv_w + zero(deg)
    int xb = (N * 64 + 255) / 256;
    int wb = (256 * 768 + 64 * 768 + 255) / 256;
    int zb = (N + 255) / 256;
    pre<<<xb + wb + zb, 256, 0, stream>>>(x, W1, W2, hstk, Wt1, Wt2, deg, xb, wb, N);

    // K2-K4: CSR
    int eb = (EP + 255) / 256;
    build_deg<<<eb, 256, 0, stream>>>(ei, E, N, deg);
    scan_deg<<<1, 1024, 0, stream>>>(deg, offs, cursor, N);
    fill_csr<<<eb, 256, 0, stream>>>(ei, E, N, cursor, csr);

    // K5: layer-1 GEMM + scores (head-major outputs), 128x64 tiles
    dim3 g1(4, (N + 127) / 128);
    gemm_scores<<<g1, 256, 0, stream>>>(hstk, Wt1, h1, a1s, a1d, es1, ed1, N);

    // K6: layer-1 aggregation (XCD-local head tables, 4 edges/wave-iter)
    int ngrp = (N + 3) / 4;
    agg1<<<ngrp * 4, 256, 0, stream>>>(h1, csr, offs, es1, ed1, b1, hstk, N);

    // K7: layer-2 GEMM + scores
    dim3 g2(1, (N + 127) / 128);
    gemm_scores<<<g2, 256, 0, stream>>>(hstk, Wt2, h2, a2s, a2d, es2, ed2, N);

    // K8: layer-2 aggregation -> out
    agg2<<<ngrp, 256, 0, stream>>>(h2, csr, offs, es2, ed2, b2, out, N);
}

// Round 7
// 246.443 us; speedup vs baseline: 1.0859x; 1.0859x over previous
//
#include <hip/hip_runtime.h>
#include <math.h>

#define NEG 0.2f

typedef __attribute__((ext_vector_type(8))) short bf16x8;
typedef __attribute__((ext_vector_type(4))) float f32x4;
typedef unsigned int u32;

__device__ inline float bf2f(unsigned short u) {
    union { unsigned int i; float f; } v; v.i = ((unsigned int)u) << 16; return v.f;
}
__device__ inline unsigned short f2bf(float f) {
    union { float f; unsigned int i; } v; v.f = f;
    unsigned int r = v.i + 0x7FFF + ((v.i >> 16) & 1);
    return (unsigned short)(r >> 16);
}
// async global->LDS, 16B/lane; LDS dest = wave-uniform base + lane*16
__device__ inline void load_lds16(const unsigned short* g, unsigned short* l) {
    __builtin_amdgcn_global_load_lds((const __attribute__((address_space(1))) u32*)g,
                                     (__attribute__((address_space(3))) u32*)l, 16, 0, 0);
}

// ============ GEMM1 (split-bf16, 128x128 tile) + fused scores1 ============
// A: [M,512] bf16 [Ah|Al]; Bt: [256,768] rows [Wh;Wh;Wl]
// C: HEAD-MAJOR [4][M][64] bf16   es/ed: HEAD-MAJOR [4][M] fp32
__global__ __launch_bounds__(256) void gemm1_scores(const unsigned short* __restrict__ A,
                                                    const unsigned short* __restrict__ Bt,
                                                    unsigned short* __restrict__ C,
                                                    const float* __restrict__ a1s,
                                                    const float* __restrict__ a1d,
                                                    float* __restrict__ es,
                                                    float* __restrict__ ed, int M) {
    __shared__ unsigned short As[128 * 32];
    __shared__ unsigned short Bs[128 * 32];
    const int tid = threadIdx.x;
    const int bm = blockIdx.y * 128, bn = blockIdx.x * 128;
    const int wave = tid >> 6, lane = tid & 63;
    const int wm = (wave >> 1) * 64, wn = (wave & 1) * 64;
    const int lm = lane & 15, kq = lane >> 4;
    const int rA = lane >> 2, cA = (lane & 3) * 8;

    f32x4 acc[4][4] = {};
    for (int k0 = 0; k0 < 768; k0 += 32) {
        const int ka = (k0 < 512) ? k0 : k0 - 512;
#pragma unroll
        for (int i = 0; i < 2; ++i) {
            int c = wave * 2 + i;
            int gr = bm + c * 16 + rA;
            if (gr >= M) gr = M - 1;  // clamp: discarded at store
            load_lds16(A + (size_t)gr * 512 + ka + cA, &As[c * 16 * 32]);
        }
#pragma unroll
        for (int i = 0; i < 2; ++i) {
            int c = wave * 2 + i;
            load_lds16(Bt + (size_t)(bn + c * 16 + rA) * 768 + k0 + cA, &Bs[c * 16 * 32]);
        }
        __syncthreads();
        bf16x8 af[4], bfr[4];
#pragma unroll
        for (int f = 0; f < 4; ++f) af[f] = *(const bf16x8*)(&As[(wm + f * 16 + lm) * 32 + kq * 8]);
#pragma unroll
        for (int f = 0; f < 4; ++f) bfr[f] = *(const bf16x8*)(&Bs[(wn + f * 16 + lm) * 32 + kq * 8]);
#pragma unroll
        for (int fr = 0; fr < 4; ++fr)
#pragma unroll
            for (int fc = 0; fc < 4; ++fc)
                acc[fr][fc] = __builtin_amdgcn_mfma_f32_16x16x32_bf16(af[fr], bfr[fc], acc[fr][fc], 0, 0, 0);
        __syncthreads();
    }
    // epilogue: each wave owns 64 cols = exactly one head
    const int head = (bn + wn) >> 6;
    float asv[4], adv[4];
#pragma unroll
    for (int fc = 0; fc < 4; ++fc) {
        asv[fc] = a1s[head * 64 + fc * 16 + lm];
        adv[fc] = a1d[head * 64 + fc * 16 + lm];
    }
    unsigned short* Ch = C + (size_t)head * M * 64;
#pragma unroll
    for (int fr = 0; fr < 4; ++fr)
#pragma unroll
        for (int i = 0; i < 4; ++i) {
            int row = bm + wm + fr * 16 + kq * 4 + i;
            float se = 0.f, de = 0.f;
#pragma unroll
            for (int fc = 0; fc < 4; ++fc) {
                float c = acc[fr][fc][i];
                se = fmaf(asv[fc], c, se);
                de = fmaf(adv[fc], c, de);
            }
#pragma unroll
            for (int off = 1; off < 16; off <<= 1) {
                se += __shfl_xor(se, off, 64);
                de += __shfl_xor(de, off, 64);
            }
            if (row < M) {
                if (lm == 0) { es[head * M + row] = se; ed[head * M + row] = de; }
#pragma unroll
                for (int fc = 0; fc < 4; ++fc)
                    Ch[(size_t)row * 64 + fc * 16 + lm] = f2bf(acc[fr][fc][i]);
            }
        }
}

// ============ GEMM2 (128x64 tile) + fused scores2 ============
__global__ __launch_bounds__(256) void gemm2_scores(const unsigned short* __restrict__ A,
                                                    const unsigned short* __restrict__ Bt,
                                                    unsigned short* __restrict__ C,
                                                    const float* __restrict__ a2s,
                                                    const float* __restrict__ a2d,
                                                    float* __restrict__ es,
                                                    float* __restrict__ ed, int M) {
    __shared__ unsigned short As[128 * 32];
    __shared__ unsigned short Bs[64 * 32];
    const int tid = threadIdx.x;
    const int bm = blockIdx.y * 128;
    const int wave = tid >> 6, lane = tid & 63;
    const int wm = wave * 32;
    const int lm = lane & 15, kq = lane >> 4;
    const int rA = lane >> 2, cA = (lane & 3) * 8;

    f32x4 acc[2][4] = {};
    for (int k0 = 0; k0 < 768; k0 += 32) {
        const int ka = (k0 < 512) ? k0 : k0 - 512;
#pragma unroll
        for (int i = 0; i < 2; ++i) {
            int c = wave * 2 + i;
            int gr = bm + c * 16 + rA;
            if (gr >= M) gr = M - 1;
            load_lds16(A + (size_t)gr * 512 + ka + cA, &As[c * 16 * 32]);
        }
        load_lds16(Bt + (size_t)(wave * 16 + rA) * 768 + k0 + cA, &Bs[wave * 16 * 32]);
        __syncthreads();
        bf16x8 af[2], bfr[4];
#pragma unroll
        for (int f = 0; f < 2; ++f) af[f] = *(const bf16x8*)(&As[(wm + f * 16 + lm) * 32 + kq * 8]);
#pragma unroll
        for (int f = 0; f < 4; ++f) bfr[f] = *(const bf16x8*)(&Bs[(f * 16 + lm) * 32 + kq * 8]);
#pragma unroll
        for (int fr = 0; fr < 2; ++fr)
#pragma unroll
            for (int fc = 0; fc < 4; ++fc)
                acc[fr][fc] = __builtin_amdgcn_mfma_f32_16x16x32_bf16(af[fr], bfr[fc], acc[fr][fc], 0, 0, 0);
        __syncthreads();
    }
    float asv[4], adv[4];
#pragma unroll
    for (int fc = 0; fc < 4; ++fc) {
        asv[fc] = a2s[fc * 16 + lm];
        adv[fc] = a2d[fc * 16 + lm];
    }
#pragma unroll
    for (int fr = 0; fr < 2; ++fr)
#pragma unroll
        for (int i = 0; i < 4; ++i) {
            int row = bm + wm + fr * 16 + kq * 4 + i;
            float se = 0.f, de = 0.f;
#pragma unroll
            for (int fc = 0; fc < 4; ++fc) {
                float c = acc[fr][fc][i];
                se = fmaf(asv[fc], c, se);
                de = fmaf(adv[fc], c, de);
            }
#pragma unroll
            for (int off = 1; off < 16; off <<= 1) {
                se += __shfl_xor(se, off, 64);
                de += __shfl_xor(de, off, 64);
            }
            if (row < M) {
                if (lm == 0) { es[row] = se; ed[row] = de; }
#pragma unroll
                for (int fc = 0; fc < 4; ++fc)
                    C[(size_t)row * 64 + fc * 16 + lm] = f2bf(acc[fr][fc][i]);
            }
        }
}

// ============ fused pre-pass: conv_x + conv_w(1&2) + zero(deg) ============
__global__ __launch_bounds__(256) void pre(const float* __restrict__ x,
                                           const float* __restrict__ W1,
                                           const float* __restrict__ W2,
                                           unsigned short* __restrict__ xs,
                                           unsigned short* __restrict__ Wt1,
                                           unsigned short* __restrict__ Wt2,
                                           int* __restrict__ deg,
                                           int xb, int wb, int N) {
    int b = blockIdx.x, tid = threadIdx.x;
    if (b < xb) {
        int i = b * 256 + tid;
        if (i >= N * 64) return;
        int e0 = i * 4;
        int node = e0 >> 8, c = e0 & 255;
        float4 f = *(const float4*)(x + e0);
        unsigned short h0 = f2bf(f.x), h1 = f2bf(f.y), h2 = f2bf(f.z), h3 = f2bf(f.w);
        uint2 hi, lo;
        hi.x = (u32)h0 | ((u32)h1 << 16);
        hi.y = (u32)h2 | ((u32)h3 << 16);
        lo.x = (u32)f2bf(f.x - bf2f(h0)) | ((u32)f2bf(f.y - bf2f(h1)) << 16);
        lo.y = (u32)f2bf(f.z - bf2f(h2)) | ((u32)f2bf(f.w - bf2f(h3)) << 16);
        *(uint2*)(xs + (size_t)node * 512 + c) = hi;
        *(uint2*)(xs + (size_t)node * 512 + 256 + c) = lo;
    } else if (b < xb + wb) {
        int i = (b - xb) * 256 + tid;
        const float* W;
        unsigned short* Wt;
        int outc;
        if (i < 256 * 768) { W = W1; Wt = Wt1; outc = 256; }
        else {
            i -= 256 * 768;
            if (i >= 64 * 768) return;
            W = W2; Wt = Wt2; outc = 64;
        }
        int n = i / 768, k = i % 768;
        int ksrc = (k < 256) ? k : (k < 512 ? k - 256 : k - 512);
        float f = W[(size_t)ksrc * outc + n];
        unsigned short h = f2bf(f);
        if (k >= 512) h = f2bf(f - bf2f(h));
        Wt[i] = h;
    } else {
        int i = (b - xb - wb) * 256 + tid;
        if (i < N) deg[i] = 0;
    }
}

// ============ CSR build ============
__global__ __launch_bounds__(256) void build_deg(const int* __restrict__ ei, int E, int Np,
                                                 int* __restrict__ deg) {
    int e = blockIdx.x * 256 + threadIdx.x;
    if (e >= E + Np) return;
    int d = (e < E) ? ei[E + e] : (e - E);
    atomicAdd(&deg[d], 1);
}

__global__ __launch_bounds__(1024) void scan_deg(const int* __restrict__ deg,
                                                 int* __restrict__ offs,
                                                 int* __restrict__ cursor, int n) {
    __shared__ int sums[1024];
    int t = threadIdx.x;
    int CH = (n + 1023) >> 10;
    int b = t * CH, e = min(b + CH, n);
    if (b > n) b = n;
    int s = 0;
    for (int i = b; i < e; ++i) s += deg[i];
    int val = s;
    sums[t] = val;
    __syncthreads();
    for (int off = 1; off < 1024; off <<= 1) {
        int o = (t >= off) ? sums[t - off] : 0;
        __syncthreads();
        val += o;
        sums[t] = val;
        __syncthreads();
    }
    int run = val - s;
    for (int i = b; i < e; ++i) {
        offs[i] = run;
        cursor[i] = run;
        run += deg[i];
    }
    if (t == 1023) offs[n] = val;
}

__global__ __launch_bounds__(256) void fill_csr(const int* __restrict__ ei, int E, int Np,
                                                int* __restrict__ cursor, int* __restrict__ csr) {
    int e = blockIdx.x * 256 + threadIdx.x;
    if (e >= E + Np) return;
    int s, d;
    if (e < E) { s = ei[e]; d = ei[E + e]; }
    else       { s = d = e - E; }
    int pos = atomicAdd(&cursor[d], 1);
    csr[pos] = s;
}

// ============ agg1: two-phase (parallel logits, pipelined gathers) ============
// wave = (node, head); h HEAD-MAJOR [4][n][64]; es/ed [4][n]
// Phase A: lane L -> p_L = exp(leaky(es[csr[j0+L]]+edst)) — ONE dep-chain / 64 edges
// Phase B: 4 groups x 16 lanes, 8 edges/iter via register shfl broadcast
__global__ __launch_bounds__(256) void agg1(const unsigned short* __restrict__ h,
                                            const int* __restrict__ csr,
                                            const int* __restrict__ offs,
                                            const float* __restrict__ es,
                                            const float* __restrict__ ed,
                                            const float* __restrict__ b1,
                                            unsigned short* __restrict__ outs, int n) {
    const int head = blockIdx.x & 3;
    const int node = (blockIdx.x >> 2) * 4 + (threadIdx.x >> 6);
    const int lane = threadIdx.x & 63;
    if (node >= n) return;
    const int grp = lane >> 4, li = lane & 15;
    const int ch = li * 4;
    const unsigned short* ht = h + (size_t)head * n * 64;
    const float* esh = es + (size_t)head * n;
    const float edst = ed[(size_t)head * n + node];
    const int j0 = offs[node], j1 = offs[node + 1];
    float z = 0.f;
    float a[4] = {};
    for (int base = j0; base < j1; base += 64) {
        const int cnt = min(64, j1 - base);
        // ---- phase A ----
        int idxl = base + lane;
        int sA = csr[idxl < j1 ? idxl : j0];
        float pA = 0.f;
        if (lane < cnt) {
            float l = esh[sA] + edst;
            l = (l > 0.f) ? l : NEG * l;
            pA = __expf(l);
        }
        float zz = pA;
#pragma unroll
        for (int off = 1; off < 64; off <<= 1) zz += __shfl_xor(zz, off, 64);
        z += zz;
        // ---- phase B: 8 edges per iteration ----
        for (int e = 0; e < cnt; e += 8) {
            int i0 = e + grp, i1 = e + grp + 4;
            int s0 = __shfl(sA, i0 & 63, 64);
            int s1 = __shfl(sA, i1 & 63, 64);
            float q0 = __shfl(pA, i0 & 63, 64);
            float q1 = __shfl(pA, i1 & 63, 64);
            float p0 = (i0 < cnt) ? q0 : 0.f;
            float p1 = (i1 < cnt) ? q1 : 0.f;
            uint2 w0 = *(const uint2*)(ht + (size_t)s0 * 64 + ch);
            uint2 w1 = *(const uint2*)(ht + (size_t)s1 * 64 + ch);
            a[0] = fmaf(p0, bf2f((unsigned short)(w0.x & 0xffffu)), a[0]);
            a[1] = fmaf(p0, bf2f((unsigned short)(w0.x >> 16)), a[1]);
            a[2] = fmaf(p0, bf2f((unsigned short)(w0.y & 0xffffu)), a[2]);
            a[3] = fmaf(p0, bf2f((unsigned short)(w0.y >> 16)), a[3]);
            a[0] = fmaf(p1, bf2f((unsigned short)(w1.x & 0xffffu)), a[0]);
            a[1] = fmaf(p1, bf2f((unsigned short)(w1.x >> 16)), a[1]);
            a[2] = fmaf(p1, bf2f((unsigned short)(w1.y & 0xffffu)), a[2]);
            a[3] = fmaf(p1, bf2f((unsigned short)(w1.y >> 16)), a[3]);
        }
    }
    // combine the 4 edge-groups
#pragma unroll
    for (int off = 16; off < 64; off <<= 1) {
#pragma unroll
        for (int c = 0; c < 4; ++c) a[c] += __shfl_xor(a[c], off, 64);
    }
    if (grp == 0) {
        float inv = 1.f / z;
        float r[4];
        unsigned short qh[4];
#pragma unroll
        for (int c = 0; c < 4; ++c) {
            r[c] = a[c] * inv + b1[head * 64 + ch + c];
            r[c] = (r[c] > 0.f) ? r[c] : (__expf(r[c]) - 1.f);  // ELU
            qh[c] = f2bf(r[c]);
        }
        uint2 hiw, low;
        hiw.x = (u32)qh[0] | ((u32)qh[1] << 16);
        hiw.y = (u32)qh[2] | ((u32)qh[3] << 16);
        low.x = (u32)f2bf(r[0] - bf2f(qh[0])) | ((u32)f2bf(r[1] - bf2f(qh[1])) << 16);
        low.y = (u32)f2bf(r[2] - bf2f(qh[2])) | ((u32)f2bf(r[3] - bf2f(qh[3])) << 16);
        // stacked [hi(256)|lo(256)] for GEMM2 split-bf16 input
        *(uint2*)(outs + (size_t)node * 512 + head * 64 + ch) = hiw;
        *(uint2*)(outs + (size_t)node * 512 + 256 + head * 64 + ch) = low;
    }
}

// ============ agg2: same two-phase structure, 1 head, fp32 out ============
__global__ __launch_bounds__(256) void agg2(const unsigned short* __restrict__ h,
                                            const int* __restrict__ csr,
                                            const int* __restrict__ offs,
                                            const float* __restrict__ es,
                                            const float* __restrict__ ed,
                                            const float* __restrict__ b2,
                                            float* __restrict__ out, int n) {
    const int node = blockIdx.x * 4 + (threadIdx.x >> 6);
    const int lane = threadIdx.x & 63;
    if (node >= n) return;
    const int grp = lane >> 4, li = lane & 15;
    const int ch = li * 4;
    const float edst = ed[node];
    const int j0 = offs[node], j1 = offs[node + 1];
    float z = 0.f;
    float a[4] = {};
    for (int base = j0; base < j1; base += 64) {
        const int cnt = min(64, j1 - base);
        int idxl = base + lane;
        int sA = csr[idxl < j1 ? idxl : j0];
        float pA = 0.f;
        if (lane < cnt) {
            float l = es[sA] + edst;
            l = (l > 0.f) ? l : NEG * l;
            pA = __expf(l);
        }
        float zz = pA;
#pragma unroll
        for (int off = 1; off < 64; off <<= 1) zz += __shfl_xor(zz, off, 64);
        z += zz;
        for (int e = 0; e < cnt; e += 8) {
            int i0 = e + grp, i1 = e + grp + 4;
            int s0 = __shfl(sA, i0 & 63, 64);
            int s1 = __shfl(sA, i1 & 63, 64);
            float q0 = __shfl(pA, i0 & 63, 64);
            float q1 = __shfl(pA, i1 & 63, 64);
            float p0 = (i0 < cnt) ? q0 : 0.f;
            float p1 = (i1 < cnt) ? q1 : 0.f;
            uint2 w0 = *(const uint2*)(h + (size_t)s0 * 64 + ch);
            uint2 w1 = *(const uint2*)(h + (size_t)s1 * 64 + ch);
            a[0] = fmaf(p0, bf2f((unsigned short)(w0.x & 0xffffu)), a[0]);
            a[1] = fmaf(p0, bf2f((unsigned short)(w0.x >> 16)), a[1]);
            a[2] = fmaf(p0, bf2f((unsigned short)(w0.y & 0xffffu)), a[2]);
            a[3] = fmaf(p0, bf2f((unsigned short)(w0.y >> 16)), a[3]);
            a[0] = fmaf(p1, bf2f((unsigned short)(w1.x & 0xffffu)), a[0]);
            a[1] = fmaf(p1, bf2f((unsigned short)(w1.x >> 16)), a[1]);
            a[2] = fmaf(p1, bf2f((unsigned short)(w1.y & 0xffffu)), a[2]);
            a[3] = fmaf(p1, bf2f((unsigned short)(w1.y >> 16)), a[3]);
        }
    }
#pragma unroll
    for (int off = 16; off < 64; off <<= 1) {
#pragma unroll
        for (int c = 0; c < 4; ++c) a[c] += __shfl_xor(a[c], off, 64);
    }
    if (grp == 0) {
        float inv = 1.f / z;
        float4 r;
        r.x = a[0] * inv + b2[ch + 0];
        r.y = a[1] * inv + b2[ch + 1];
        r.z = a[2] * inv + b2[ch + 2];
        r.w = a[3] * inv + b2[ch + 3];
        *(float4*)(out + (size_t)node * 64 + ch) = r;
    }
}

// ============ launch ============
extern "C" void kernel_launch(void* const* d_in, const int* in_sizes, int n_in,
                              void* d_out, int out_size, void* d_ws, size_t ws_size,
                              hipStream_t stream) {
    const float* x   = (const float*)d_in[0];
    const int*   ei  = (const int*)d_in[1];
    const float* W1  = (const float*)d_in[2];
    const float* a1s = (const float*)d_in[3];
    const float* a1d = (const float*)d_in[4];
    const float* b1  = (const float*)d_in[5];
    const float* W2  = (const float*)d_in[6];
    const float* a2s = (const float*)d_in[7];
    const float* a2d = (const float*)d_in[8];
    const float* b2  = (const float*)d_in[9];
    float* out = (float*)d_out;

    const int N = in_sizes[0] / 256;   // 20000
    const int E = in_sizes[1] / 2;     // 320000
    const int EP = E + N;

    char* p = (char*)d_ws;
    auto take = [&](size_t bytes) {
        char* r = p;
        p += (bytes + 255) & ~(size_t)255;
        return r;
    };
    int* deg    = (int*)take((size_t)N * 4);
    int* offs   = (int*)take((size_t)(N + 1) * 4);
    int* cursor = (int*)take((size_t)N * 4);
    int* csr    = (int*)take((size_t)EP * 4);
    unsigned short* hstk = (unsigned short*)take((size_t)N * 512 * 2); // x' then h1a' (aliased)
    unsigned short* Wt1  = (unsigned short*)take((size_t)256 * 768 * 2);
    unsigned short* Wt2  = (unsigned short*)take((size_t)64 * 768 * 2);
    unsigned short* h1   = (unsigned short*)take((size_t)N * 256 * 2);  // head-major [4][N][64]
    unsigned short* h2   = (unsigned short*)take((size_t)N * 64 * 2);
    float* es1 = (float*)take((size_t)N * 4 * 4);  // head-major [4][N]
    float* ed1 = (float*)take((size_t)N * 4 * 4);
    float* es2 = (float*)take((size_t)N * 4);
    float* ed2 = (float*)take((size_t)N * 4);

    // K1: conv_x + conv_w + zero(deg)
    int xb = (N * 64 + 255) / 256;
    int wb = (256 * 768 + 64 * 768 + 255) / 256;
    int zb = (N + 255) / 256;
    pre<<<xb + wb + zb, 256, 0, stream>>>(x, W1, W2, hstk, Wt1, Wt2, deg, xb, wb, N);

    // K2-K4: CSR
    int eb = (EP + 255) / 256;
    build_deg<<<eb, 256, 0, stream>>>(ei, E, N, deg);
    scan_deg<<<1, 1024, 0, stream>>>(deg, offs, cursor, N);
    fill_csr<<<eb, 256, 0, stream>>>(ei, E, N, cursor, csr);

    // K5: layer-1 GEMM + scores (head-major outputs), 128x128 tiles
    dim3 g1(2, (N + 127) / 128);
    gemm1_scores<<<g1, 256, 0, stream>>>(hstk, Wt1, h1, a1s, a1d, es1, ed1, N);

    // K6: layer-1 aggregation (two-phase, XCD-local head tables)
    int ngrp = (N + 3) / 4;
    agg1<<<ngrp * 4, 256, 0, stream>>>(h1, csr, offs, es1, ed1, b1, hstk, N);

    // K7: layer-2 GEMM + scores
    dim3 g2(1, (N + 127) / 128);
    gemm2_scores<<<g2, 256, 0, stream>>>(hstk, Wt2, h2, a2s, a2d, es2, ed2, N);

    // K8: layer-2 aggregation -> out
    agg2<<<ngrp, 256, 0, stream>>>(h2, csr, offs, es2, ed2, b2, out, N);
}